// Round 19
// baseline (277.488 us; speedup 1.0000x reference)
//
#include <hip/hip_runtime.h>
#include <hip/hip_fp16.h>

#define NEGS 0.2f
#define NB_AGGR 2048
#define NSHAD 16
#define NB_CSR 2048   // 8 XCD groups x 256 blocks (full device residency)
#define CAP 64        // padded CSR row capacity; P(Poisson(16) >= 64) ~ e^-40

typedef _Float16 f16x8 __attribute__((ext_vector_type(8)));
typedef float f32x2 __attribute__((ext_vector_type(2)));
typedef float f32x4 __attribute__((ext_vector_type(4)));

__device__ __forceinline__ float lrelu(float x){ return x > 0.f ? x : NEGS*x; }
__device__ __forceinline__ float sel4(float4 v, int h){
    float lo = (h & 1) ? v.y : v.x;
    float hi = (h & 1) ? v.w : v.z;
    return (h & 2) ? hi : lo;
}

// ---- fp8 e4m3 (OCP) pack ----
__device__ __forceinline__ unsigned char f32_to_e4m3(float x){
    union { _Float16 f; unsigned short u; } c; c.f = (_Float16)x;
    unsigned u = c.u, s = (u >> 8) & 0x80, a = u & 0x7fff;
    if (a < 0x2400) return (unsigned char)s;      // |x| < 2^-6 -> signed zero
    a += 0x40;                                    // round to nearest (3-bit mantissa)
    unsigned e = (a >> 10) - 8;                   // f16 exp field -> e4 field (bias 15->7)
    unsigned m = (a >> 7) & 7;
    return (unsigned char)(s | (e << 3) | m);
}
// ---- fp8 pair -> 2 f32 via HW v_cvt_pk_f32_fp8 (word_sel is a constant) ----
template<bool HI>
__device__ __forceinline__ float2 fp8x2_to_f2(unsigned int packed){
#if __has_builtin(__builtin_amdgcn_cvt_pk_f32_fp8)
    f32x2 r = __builtin_amdgcn_cvt_pk_f32_fp8((int)packed, HI);
    return make_float2(r[0], r[1]);
#else
    unsigned short sv = HI ? (unsigned short)(packed >> 16) : (unsigned short)(packed & 0xffff);
    unsigned b0 = sv & 0xff, b1 = (sv >> 8) & 0xff;
    unsigned t0 = b0 & 0x7f, t1 = b1 & 0x7f;
    unsigned short u0 = (unsigned short)(((b0 & 0x80) << 8) | (t0 ? ((t0 + 64) << 7) : 0));
    unsigned short u1 = (unsigned short)(((b1 & 0x80) << 8) | (t1 ? ((t1 + 64) << 7) : 0));
    union { unsigned short u; _Float16 f; } c0, c1; c0.u = u0; c1.u = u1;
    return make_float2((float)c0.f, (float)c1.f);
#endif
}

// ---------------- W convert: WH[col][k] fp16, col 0-127 = Wsrc, 128-255 = Wres ----
__global__ __launch_bounds__(256) void k_wcvt(const float* __restrict__ Wsrc,
        const float* __restrict__ Wres, _Float16* __restrict__ WH){
    int t = blockIdx.x*256 + threadIdx.x;   // 0..32767
    if (t < 16384)      WH[t] = (_Float16)Wsrc[t];
    else if (t < 32768) WH[t] = (_Float16)Wres[t - 16384];
}

// ---------------- MFMA GEMM: [xp8|res] = feats(fp16) @ WH^T -----------------------
__global__ __launch_bounds__(256, 3) void k_gemm(const float* __restrict__ feats,
        const _Float16* __restrict__ WH,
        const float* __restrict__ att_s, const float* __restrict__ att_d,
        unsigned char* __restrict__ xp8, float* __restrict__ res,
        float* __restrict__ a_src, float* __restrict__ a_dst, int n){
    __shared__ _Float16 As[8192];           // 16 frames x 64 lanes x 8 halfs
    int t = threadIdx.x;
    int n0 = blockIdx.x * 64;
    const float4* f4 = (const float4*)feats;
    #pragma unroll
    for (int i = 0; i < 8; ++i){
        int idx = t + i*256;                // 2048 float4 chunks (row, c4)
        int row = idx >> 5, c4 = idx & 31;
        float4 v = make_float4(0.f,0.f,0.f,0.f);
        if (n0 + row < n) v = f4[(size_t)(n0+row)*32 + c4];
        int mt = row >> 4, l15r = row & 15;
        int kk = c4 >> 3, l4r = (c4 >> 1) & 3, jr = (c4 & 1)*4;
        int off = (mt*4 + kk)*512 + (l4r*16 + l15r)*8 + jr;
        As[off+0] = (_Float16)v.x; As[off+1] = (_Float16)v.y;
        As[off+2] = (_Float16)v.z; As[off+3] = (_Float16)v.w;
    }
    __syncthreads();
    int w = t >> 6, lane = t & 63;
    int l15 = lane & 15, l4 = lane >> 4;
    f32x4 acc[4][4];
    #pragma unroll
    for (int mt = 0; mt < 4; ++mt)
        #pragma unroll
        for (int nt = 0; nt < 4; ++nt)
            acc[mt][nt] = (f32x4){0.f,0.f,0.f,0.f};
    const f16x8* Bp = (const f16x8*)WH;     // frag = Bp[col*16 + kk*4 + l4]
    #pragma unroll
    for (int kk = 0; kk < 4; ++kk){
        f16x8 a[4], b[4];
        #pragma unroll
        for (int mt = 0; mt < 4; ++mt)
            a[mt] = *(const f16x8*)&As[(mt*4 + kk)*512 + lane*8];
        #pragma unroll
        for (int nt = 0; nt < 4; ++nt){
            int col = w*64 + nt*16 + l15;
            b[nt] = Bp[col*16 + kk*4 + l4];
        }
        #pragma unroll
        for (int mt = 0; mt < 4; ++mt)
            #pragma unroll
            for (int nt = 0; nt < 4; ++nt)
                acc[mt][nt] = __builtin_amdgcn_mfma_f32_16x16x32_f16(a[mt], b[nt], acc[mt][nt], 0, 0, 0);
    }
    if (w < 2){
        // xp columns: fp8 byte stores + fused attention dots (heads 2w, 2w+1)
        float as0 = att_s[w*64 + l15],      as1 = att_s[w*64 + 16 + l15];
        float as2 = att_s[w*64 + 32 + l15], as3 = att_s[w*64 + 48 + l15];
        float ad0 = att_d[w*64 + l15],      ad1 = att_d[w*64 + 16 + l15];
        float ad2 = att_d[w*64 + 32 + l15], ad3 = att_d[w*64 + 48 + l15];
        #pragma unroll
        for (int mt = 0; mt < 4; ++mt){
            #pragma unroll
            for (int reg = 0; reg < 4; ++reg){
                int node = n0 + mt*16 + l4*4 + reg;
                float v0 = acc[mt][0][reg], v1 = acc[mt][1][reg];
                float v2 = acc[mt][2][reg], v3 = acc[mt][3][reg];
                if (node < n){
                    unsigned char* xp = xp8 + (size_t)node*128 + w*64 + l15;
                    xp[0]  = f32_to_e4m3(v0);
                    xp[16] = f32_to_e4m3(v1);
                    xp[32] = f32_to_e4m3(v2);
                    xp[48] = f32_to_e4m3(v3);
                }
                float ps0 = v0*as0 + v1*as1, ps1 = v2*as2 + v3*as3;
                float pd0 = v0*ad0 + v1*ad1, pd1 = v2*ad2 + v3*ad3;
                #pragma unroll
                for (int off = 1; off <= 8; off <<= 1){
                    ps0 += __shfl_xor(ps0, off); ps1 += __shfl_xor(ps1, off);
                    pd0 += __shfl_xor(pd0, off); pd1 += __shfl_xor(pd1, off);
                }
                if (l15 == 0 && node < n){
                    a_src[node*4 + 2*w]     = ps0;
                    a_src[node*4 + 2*w + 1] = ps1;
                    a_dst[node*4 + 2*w]     = pd0;
                    a_dst[node*4 + 2*w + 1] = pd1;
                }
            }
        }
    } else {
        // res columns (128-255): f32 store to out
        int cbase = (w-2)*64;
        #pragma unroll
        for (int mt = 0; mt < 4; ++mt){
            #pragma unroll
            for (int reg = 0; reg < 4; ++reg){
                int node = n0 + mt*16 + l4*4 + reg;
                if (node < n){
                    float* rp = res + (size_t)node*128 + cbase + l15;
                    rp[0]  = acc[mt][0][reg];
                    rp[16] = acc[mt][1][reg];
                    rp[32] = acc[mt][2][reg];
                    rp[48] = acc[mt][3][reg];
                }
            }
        }
    }
}

// ---------------- padded-CSR scatter (XCD-range partitioned, batched loads) -------
__global__ __launch_bounds__(256) void k_scatter(const int* __restrict__ ei,
        int* __restrict__ cursor, int* __restrict__ nbr, int e, int n){
    int g  = blockIdx.x & 7;
    int bi = blockIdx.x >> 3;
    int chunk = (n + 7) >> 3;
    int lo = g*chunk, hi = min(n, lo + chunk);
    int tid = bi*256 + (int)threadIdx.x;          // within group
    const int4* d4 = (const int4*)(ei + e);       // dst stream as int4
    int nv4 = e >> 2;
    const int stride = (NB_CSR/8)*256*2;          // int4 chunks per group pass
    for (int q = tid*2; q < nv4; q += stride){
        int4 a = d4[q];
        int4 b = (q+1 < nv4) ? d4[q+1] : make_int4(-1,-1,-1,-1);
        int ds[8] = {a.x, a.y, a.z, a.w, b.x, b.y, b.z, b.w};
        #pragma unroll
        for (int k = 0; k < 8; ++k){
            int d = ds[k];
            if (d >= lo && d < hi){
                int s = ei[q*4 + k];
                int pos = atomicAdd(&cursor[d], 1);
                if (pos < CAP) nbr[(size_t)d*CAP + pos] = s;
            }
        }
    }
    if (blockIdx.x == 0 && (int)threadIdx.x < (e & 3)){
        int i = (e & ~3) + (int)threadIdx.x;
        int d = ei[e + i];
        int s = ei[i];
        int pos = atomicAdd(&cursor[d], 1);
        if (pos < CAP) nbr[(size_t)d*CAP + pos] = s;
    }
}

// ---------------- fused softmax + aggregation + residual + BN partials ----------------
// One wave per node, fp8 rows (128B), chunk 32 (round-16 config — measured best).
// __launch_bounds__(256, 8): rounds 13-18 pinned at ~42% occupancy (the ",4" capped
// residency at 16 waves/CU) while nothing else saturated => latency-bound on resident-
// wave count. VGPR=48 < 64-cliff and LDS 6KBx8=48KB both allow 8 blocks/CU.
__global__ __launch_bounds__(256, 8) void k_aggr(const unsigned char* __restrict__ xp8,
        const float* __restrict__ a_src, const float* __restrict__ a_dst,
        const int* __restrict__ cursor, const int* __restrict__ nbr,
        const float* __restrict__ bias, float* __restrict__ out,
        float* __restrict__ gshad, int n){
    __shared__ float lsum[4][128];
    __shared__ float lsq[4][128];
    __shared__ float wlds[4][32][4];          // per-wave weight tile
    int w = threadIdx.x >> 6, lane = threadIdx.x & 63;
    int sub = lane & 15;        // 8B slot within 128B row (8 fp8 channels)
    int e4  = lane >> 4;        // edge group 0..3
    int h   = sub >> 2;         // head (8 channels per lane, 32 per head)
    const float4* a4 = (const float4*)a_src;
    const uint2* x8  = (const uint2*)xp8;     // 16 uint2 per 128B row
    float psum[8], psq[8];
    #pragma unroll
    for (int k = 0; k < 8; ++k){ psum[k]=0.f; psq[k]=0.f; }
    int ngroups = (n + 3) >> 2;
    for (int grp = blockIdx.x; grp < ngroups; grp += NB_AGGR){
        int node = grp*4 + w;
        if (node >= n) continue;
        float4 ad4 = *(const float4*)(a_dst + node*4);
        float adh = sel4(ad4, h);
        int deg = min(cursor[node], CAP);
        const int* nrow = nbr + (size_t)node*CAP;
        float acc[8];
        #pragma unroll
        for (int k = 0; k < 8; ++k) acc[k] = 0.f;
        float ssum = (e4 == 0) ? __expf(lrelu(a_src[node*4 + h] + adh)) : 0.f;
        float ws = ssum;                              // self weight (e4==0 lanes)
        uint2 xsraw = x8[(size_t)node*16 + sub];      // self row slot (fp8)
        for (int ch0 = 0; ch0 < deg; ch0 += 32){
            int idx = ch0 + lane;
            if (idx > deg-1) idx = deg-1;
            int sidv = (lane < 32) ? nrow[idx] : node;
            float4 av = a4[sidv];
            if (lane < 32){
                float4 w4;
                w4.x = __expf(lrelu(av.x + ad4.x));
                w4.y = __expf(lrelu(av.y + ad4.y));
                w4.z = __expf(lrelu(av.z + ad4.z));
                w4.w = __expf(lrelu(av.w + ad4.w));
                *(float4*)&wlds[w][lane][0] = w4;
            }
            __builtin_amdgcn_wave_barrier();          // order LDS write->read in-wave
            int sid[8];
            #pragma unroll
            for (int p = 0; p < 8; ++p) sid[p] = __shfl(sidv, p*4 + e4);
            uint2 xr[8];
            #pragma unroll
            for (int p = 0; p < 8; ++p) xr[p] = x8[(size_t)sid[p]*16 + sub];
            #pragma unroll
            for (int p = 0; p < 8; ++p){
                int j = p*4 + e4;
                float wgt = ((ch0 + j) < deg) ? wlds[w][j][h] : 0.f;
                ssum += wgt;
                float2 c0 = fp8x2_to_f2<false>(xr[p].x);
                float2 c1 = fp8x2_to_f2<true >(xr[p].x);
                float2 c2 = fp8x2_to_f2<false>(xr[p].y);
                float2 c3 = fp8x2_to_f2<true >(xr[p].y);
                acc[0] += wgt*c0.x; acc[1] += wgt*c0.y;
                acc[2] += wgt*c1.x; acc[3] += wgt*c1.y;
                acc[4] += wgt*c2.x; acc[5] += wgt*c2.y;
                acc[6] += wgt*c3.x; acc[7] += wgt*c3.y;
            }
        }
        // combine the 4 edge groups
        #pragma unroll
        for (int off = 16; off <= 32; off <<= 1){
            #pragma unroll
            for (int k = 0; k < 8; ++k) acc[k] += __shfl_xor(acc[k], off);
            ssum += __shfl_xor(ssum, off);
        }
        float inv = 1.f/(ssum + 1e-16f);
        if (e4 == 0){
            float fs[8];
            float2 s0 = fp8x2_to_f2<false>(xsraw.x);
            float2 s1 = fp8x2_to_f2<true >(xsraw.x);
            float2 s2 = fp8x2_to_f2<false>(xsraw.y);
            float2 s3 = fp8x2_to_f2<true >(xsraw.y);
            fs[0]=s0.x; fs[1]=s0.y; fs[2]=s1.x; fs[3]=s1.y;
            fs[4]=s2.x; fs[5]=s2.y; fs[6]=s3.x; fs[7]=s3.y;
            float4 r0 = *(const float4*)(out + (size_t)node*128 + sub*8);
            float4 r1 = *(const float4*)(out + (size_t)node*128 + sub*8 + 4);
            float4 b0 = *(const float4*)(bias + sub*8);
            float4 b1 = *(const float4*)(bias + sub*8 + 4);
            float o[8];
            o[0] = (acc[0]+ws*fs[0])*inv + r0.x + b0.x; o[1] = (acc[1]+ws*fs[1])*inv + r0.y + b0.y;
            o[2] = (acc[2]+ws*fs[2])*inv + r0.z + b0.z; o[3] = (acc[3]+ws*fs[3])*inv + r0.w + b0.w;
            o[4] = (acc[4]+ws*fs[4])*inv + r1.x + b1.x; o[5] = (acc[5]+ws*fs[5])*inv + r1.y + b1.y;
            o[6] = (acc[6]+ws*fs[6])*inv + r1.z + b1.z; o[7] = (acc[7]+ws*fs[7])*inv + r1.w + b1.w;
            *(float4*)(out + (size_t)node*128 + sub*8)     = make_float4(o[0],o[1],o[2],o[3]);
            *(float4*)(out + (size_t)node*128 + sub*8 + 4) = make_float4(o[4],o[5],o[6],o[7]);
            #pragma unroll
            for (int k = 0; k < 8; ++k){ psum[k] += o[k]; psq[k] += o[k]*o[k]; }
        }
    }
    // epilogue: block-combine in LDS, one atomic per thread into a shadow copy
    if (e4 == 0){
        *(float4*)&lsum[w][sub*8]   = make_float4(psum[0],psum[1],psum[2],psum[3]);
        *(float4*)&lsum[w][sub*8+4] = make_float4(psum[4],psum[5],psum[6],psum[7]);
        *(float4*)&lsq[w][sub*8]    = make_float4(psq[0],psq[1],psq[2],psq[3]);
        *(float4*)&lsq[w][sub*8+4]  = make_float4(psq[4],psq[5],psq[6],psq[7]);
    }
    __syncthreads();
    int t = threadIdx.x;
    float* shad = gshad + (blockIdx.x & (NSHAD-1))*256;
    if (t < 128){
        float s = lsum[0][t]+lsum[1][t]+lsum[2][t]+lsum[3][t];
        atomicAdd(&shad[t], s);
    } else {
        int c = t-128;
        float s = lsq[0][c]+lsq[1][c]+lsq[2][c]+lsq[3][c];
        atomicAdd(&shad[128 + c], s);
    }
}

// ---------------- BN finalize ----------------
__global__ void k_bnfin(const float* __restrict__ gshad,
        const float* __restrict__ gamma, const float* __restrict__ beta,
        float* __restrict__ scale, float* __restrict__ shift, int n){
    int t = threadIdx.x;
    if (t < 128){
        float s = 0.f, q = 0.f;
        #pragma unroll
        for (int c = 0; c < NSHAD; ++c){
            s += gshad[c*256 + t];
            q += gshad[c*256 + 128 + t];
        }
        float mu  = s/(float)n;
        float var = q/(float)n - mu*mu;
        float inv = rsqrtf(var + 1e-5f);
        float sc  = inv*gamma[t];
        scale[t] = sc;
        shift[t] = beta[t] - mu*sc;
    }
}

__global__ __launch_bounds__(256) void k_bnapply(float* __restrict__ out,
        const float* __restrict__ scale, const float* __restrict__ shift, long total4){
    __shared__ float sc[128], sh[128];
    if (threadIdx.x < 128){ sc[threadIdx.x]=scale[threadIdx.x]; sh[threadIdx.x]=shift[threadIdx.x]; }
    __syncthreads();
    long i = (long)blockIdx.x*blockDim.x + threadIdx.x;
    if (i < total4){
        float4* o4 = (float4*)out;
        float4 v = o4[i];
        int c = (int)((i & 31) * 4);
        v.x = v.x*sc[c+0]+sh[c+0];
        v.y = v.y*sc[c+1]+sh[c+1];
        v.z = v.z*sc[c+2]+sh[c+2];
        v.w = v.w*sc[c+3]+sh[c+3];
        o4[i]=v;
    }
}

extern "C" void kernel_launch(void* const* d_in, const int* in_sizes, int n_in,
                              void* d_out, int out_size, void* d_ws, size_t ws_size,
                              hipStream_t stream){
    const float* feats      = (const float*)d_in[0];
    const int* ei           = (const int*)d_in[1];   // harness converts int64 -> int32
    const float* Wsrc       = (const float*)d_in[2];
    const float* att_s      = (const float*)d_in[3];
    const float* att_d      = (const float*)d_in[4];
    const float* Wres       = (const float*)d_in[5];
    const float* bias       = (const float*)d_in[6];
    const float* gamma      = (const float*)d_in[7];
    const float* beta       = (const float*)d_in[8];
    int n = in_sizes[0]/128;
    int e = in_sizes[1]/2;
    float* out = (float*)d_out;

    char* w = (char*)d_ws;
    unsigned char* xp8 = (unsigned char*)w; w += (size_t)n*128;
    float* a_src = (float*)w; w += (size_t)n*4*4;
    float* a_dst = (float*)w; w += (size_t)n*4*4;
    int*   cursor= (int*)w;   w += (size_t)n*4;
    int*   nbr   = (int*)w;   w += (size_t)n*CAP*4;
    float* gshad = (float*)w; w += (size_t)NSHAD*256*4;
    float* scale = (float*)w; w += 512;
    float* shift = (float*)w; w += 512;
    _Float16* WH = (_Float16*)w; w += 32768*2;

    hipMemsetAsync(cursor, 0, (size_t)n*4, stream);
    hipMemsetAsync(gshad,  0, (size_t)NSHAD*256*4, stream);

    k_wcvt<<<dim3(128), 256, 0, stream>>>(Wsrc, Wres, WH);
    k_gemm<<<dim3((n+63)/64), 256, 0, stream>>>(feats, WH, att_s, att_d, xp8, out, a_src, a_dst, n);
    k_scatter<<<dim3(NB_CSR), 256, 0, stream>>>(ei, cursor, nbr, e, n);
    k_aggr<<<dim3(NB_AGGR), 256, 0, stream>>>(xp8, a_src, a_dst, cursor, nbr, bias, out, gshad, n);
    k_bnfin<<<dim3(1), 128, 0, stream>>>(gshad, gamma, beta, scale, shift, n);
    long total4 = (long)n*32;
    k_bnapply<<<dim3((int)((total4+255)/256)), 256, 0, stream>>>(out, scale, shift, total4);
}

// Round 20
// 222.431 us; speedup vs baseline: 1.2475x; 1.2475x over previous
//
#include <hip/hip_runtime.h>
#include <hip/hip_fp16.h>

#define NEGS 0.2f
#define NB_AGGR 2048
#define NSHAD 16
#define NB_CSR 2048   // 8 XCD groups x 256 blocks (full device residency)
#define CAP 64        // padded CSR row capacity; P(Poisson(16) >= 64) ~ e^-40

typedef _Float16 f16x8 __attribute__((ext_vector_type(8)));
typedef float f32x2 __attribute__((ext_vector_type(2)));
typedef float f32x4 __attribute__((ext_vector_type(4)));

__device__ __forceinline__ float lrelu(float x){ return x > 0.f ? x : NEGS*x; }
__device__ __forceinline__ float sel4(float4 v, int h){
    float lo = (h & 1) ? v.y : v.x;
    float hi = (h & 1) ? v.w : v.z;
    return (h & 2) ? hi : lo;
}

// ---- fp8 e4m3 (OCP) pack ----
__device__ __forceinline__ unsigned char f32_to_e4m3(float x){
    union { _Float16 f; unsigned short u; } c; c.f = (_Float16)x;
    unsigned u = c.u, s = (u >> 8) & 0x80, a = u & 0x7fff;
    if (a < 0x2400) return (unsigned char)s;      // |x| < 2^-6 -> signed zero
    a += 0x40;                                    // round to nearest (3-bit mantissa)
    unsigned e = (a >> 10) - 8;                   // f16 exp field -> e4 field (bias 15->7)
    unsigned m = (a >> 7) & 7;
    return (unsigned char)(s | (e << 3) | m);
}
// ---- fp8 pair -> 2 f32 via HW v_cvt_pk_f32_fp8 (word_sel is a constant) ----
template<bool HI>
__device__ __forceinline__ float2 fp8x2_to_f2(unsigned int packed){
#if __has_builtin(__builtin_amdgcn_cvt_pk_f32_fp8)
    f32x2 r = __builtin_amdgcn_cvt_pk_f32_fp8((int)packed, HI);
    return make_float2(r[0], r[1]);
#else
    unsigned short sv = HI ? (unsigned short)(packed >> 16) : (unsigned short)(packed & 0xffff);
    unsigned b0 = sv & 0xff, b1 = (sv >> 8) & 0xff;
    unsigned t0 = b0 & 0x7f, t1 = b1 & 0x7f;
    unsigned short u0 = (unsigned short)(((b0 & 0x80) << 8) | (t0 ? ((t0 + 64) << 7) : 0));
    unsigned short u1 = (unsigned short)(((b1 & 0x80) << 8) | (t1 ? ((t1 + 64) << 7) : 0));
    union { unsigned short u; _Float16 f; } c0, c1; c0.u = u0; c1.u = u1;
    return make_float2((float)c0.f, (float)c1.f);
#endif
}

// ---------------- W convert: WH[col][k] fp16, col 0-127 = Wsrc, 128-255 = Wres ----
__global__ __launch_bounds__(256) void k_wcvt(const float* __restrict__ Wsrc,
        const float* __restrict__ Wres, _Float16* __restrict__ WH){
    int t = blockIdx.x*256 + threadIdx.x;   // 0..32767
    if (t < 16384)      WH[t] = (_Float16)Wsrc[t];
    else if (t < 32768) WH[t] = (_Float16)Wres[t - 16384];
}

// ---------------- MFMA GEMM: [xp8|res] = feats(fp16) @ WH^T -----------------------
__global__ __launch_bounds__(256, 3) void k_gemm(const float* __restrict__ feats,
        const _Float16* __restrict__ WH,
        const float* __restrict__ att_s, const float* __restrict__ att_d,
        unsigned char* __restrict__ xp8, float* __restrict__ res,
        float* __restrict__ a_src, float* __restrict__ a_dst, int n){
    __shared__ _Float16 As[8192];           // 16 frames x 64 lanes x 8 halfs
    int t = threadIdx.x;
    int n0 = blockIdx.x * 64;
    const float4* f4 = (const float4*)feats;
    #pragma unroll
    for (int i = 0; i < 8; ++i){
        int idx = t + i*256;                // 2048 float4 chunks (row, c4)
        int row = idx >> 5, c4 = idx & 31;
        float4 v = make_float4(0.f,0.f,0.f,0.f);
        if (n0 + row < n) v = f4[(size_t)(n0+row)*32 + c4];
        int mt = row >> 4, l15r = row & 15;
        int kk = c4 >> 3, l4r = (c4 >> 1) & 3, jr = (c4 & 1)*4;
        int off = (mt*4 + kk)*512 + (l4r*16 + l15r)*8 + jr;
        As[off+0] = (_Float16)v.x; As[off+1] = (_Float16)v.y;
        As[off+2] = (_Float16)v.z; As[off+3] = (_Float16)v.w;
    }
    __syncthreads();
    int w = t >> 6, lane = t & 63;
    int l15 = lane & 15, l4 = lane >> 4;
    f32x4 acc[4][4];
    #pragma unroll
    for (int mt = 0; mt < 4; ++mt)
        #pragma unroll
        for (int nt = 0; nt < 4; ++nt)
            acc[mt][nt] = (f32x4){0.f,0.f,0.f,0.f};
    const f16x8* Bp = (const f16x8*)WH;     // frag = Bp[col*16 + kk*4 + l4]
    #pragma unroll
    for (int kk = 0; kk < 4; ++kk){
        f16x8 a[4], b[4];
        #pragma unroll
        for (int mt = 0; mt < 4; ++mt)
            a[mt] = *(const f16x8*)&As[(mt*4 + kk)*512 + lane*8];
        #pragma unroll
        for (int nt = 0; nt < 4; ++nt){
            int col = w*64 + nt*16 + l15;
            b[nt] = Bp[col*16 + kk*4 + l4];
        }
        #pragma unroll
        for (int mt = 0; mt < 4; ++mt)
            #pragma unroll
            for (int nt = 0; nt < 4; ++nt)
                acc[mt][nt] = __builtin_amdgcn_mfma_f32_16x16x32_f16(a[mt], b[nt], acc[mt][nt], 0, 0, 0);
    }
    if (w < 2){
        // xp columns: fp8 byte stores + fused attention dots (heads 2w, 2w+1)
        float as0 = att_s[w*64 + l15],      as1 = att_s[w*64 + 16 + l15];
        float as2 = att_s[w*64 + 32 + l15], as3 = att_s[w*64 + 48 + l15];
        float ad0 = att_d[w*64 + l15],      ad1 = att_d[w*64 + 16 + l15];
        float ad2 = att_d[w*64 + 32 + l15], ad3 = att_d[w*64 + 48 + l15];
        #pragma unroll
        for (int mt = 0; mt < 4; ++mt){
            #pragma unroll
            for (int reg = 0; reg < 4; ++reg){
                int node = n0 + mt*16 + l4*4 + reg;
                float v0 = acc[mt][0][reg], v1 = acc[mt][1][reg];
                float v2 = acc[mt][2][reg], v3 = acc[mt][3][reg];
                if (node < n){
                    unsigned char* xp = xp8 + (size_t)node*128 + w*64 + l15;
                    xp[0]  = f32_to_e4m3(v0);
                    xp[16] = f32_to_e4m3(v1);
                    xp[32] = f32_to_e4m3(v2);
                    xp[48] = f32_to_e4m3(v3);
                }
                float ps0 = v0*as0 + v1*as1, ps1 = v2*as2 + v3*as3;
                float pd0 = v0*ad0 + v1*ad1, pd1 = v2*ad2 + v3*ad3;
                #pragma unroll
                for (int off = 1; off <= 8; off <<= 1){
                    ps0 += __shfl_xor(ps0, off); ps1 += __shfl_xor(ps1, off);
                    pd0 += __shfl_xor(pd0, off); pd1 += __shfl_xor(pd1, off);
                }
                if (l15 == 0 && node < n){
                    a_src[node*4 + 2*w]     = ps0;
                    a_src[node*4 + 2*w + 1] = ps1;
                    a_dst[node*4 + 2*w]     = pd0;
                    a_dst[node*4 + 2*w + 1] = pd1;
                }
            }
        }
    } else {
        // res columns (128-255): f32 store to out
        int cbase = (w-2)*64;
        #pragma unroll
        for (int mt = 0; mt < 4; ++mt){
            #pragma unroll
            for (int reg = 0; reg < 4; ++reg){
                int node = n0 + mt*16 + l4*4 + reg;
                if (node < n){
                    float* rp = res + (size_t)node*128 + cbase + l15;
                    rp[0]  = acc[mt][0][reg];
                    rp[16] = acc[mt][1][reg];
                    rp[32] = acc[mt][2][reg];
                    rp[48] = acc[mt][3][reg];
                }
            }
        }
    }
}

// ---------------- padded-CSR scatter (XCD-range partitioned, batched loads) -------
__global__ __launch_bounds__(256) void k_scatter(const int* __restrict__ ei,
        int* __restrict__ cursor, int* __restrict__ nbr, int e, int n){
    int g  = blockIdx.x & 7;
    int bi = blockIdx.x >> 3;
    int chunk = (n + 7) >> 3;
    int lo = g*chunk, hi = min(n, lo + chunk);
    int tid = bi*256 + (int)threadIdx.x;          // within group
    const int4* d4 = (const int4*)(ei + e);       // dst stream as int4
    int nv4 = e >> 2;
    const int stride = (NB_CSR/8)*256*2;          // int4 chunks per group pass
    for (int q = tid*2; q < nv4; q += stride){
        int4 a = d4[q];
        int4 b = (q+1 < nv4) ? d4[q+1] : make_int4(-1,-1,-1,-1);
        int ds[8] = {a.x, a.y, a.z, a.w, b.x, b.y, b.z, b.w};
        #pragma unroll
        for (int k = 0; k < 8; ++k){
            int d = ds[k];
            if (d >= lo && d < hi){
                int s = ei[q*4 + k];
                int pos = atomicAdd(&cursor[d], 1);
                if (pos < CAP) nbr[(size_t)d*CAP + pos] = s;
            }
        }
    }
    if (blockIdx.x == 0 && (int)threadIdx.x < (e & 3)){
        int i = (e & ~3) + (int)threadIdx.x;
        int d = ei[e + i];
        int s = ei[i];
        int pos = atomicAdd(&cursor[d], 1);
        if (pos < CAP) nbr[(size_t)d*CAP + pos] = s;
    }
}

// ---------------- fused softmax + aggregation + residual + BN partials ----------------
// One wave per node, fp8 rows (128B), chunk 32, __launch_bounds__(256,4):
// the measured concurrency sweet spot. Round 19 proved (256,8) doubles occupancy
// but squeezes VGPR 48->32 (burst serialization) and doubles FETCH (L2 thrash):
// 95 -> 155us. Round 18 proved chunk 16 is also slower (101us). Keep this config.
__global__ __launch_bounds__(256, 4) void k_aggr(const unsigned char* __restrict__ xp8,
        const float* __restrict__ a_src, const float* __restrict__ a_dst,
        const int* __restrict__ cursor, const int* __restrict__ nbr,
        const float* __restrict__ bias, float* __restrict__ out,
        float* __restrict__ gshad, int n){
    __shared__ float lsum[4][128];
    __shared__ float lsq[4][128];
    __shared__ float wlds[4][32][4];          // per-wave weight tile
    int w = threadIdx.x >> 6, lane = threadIdx.x & 63;
    int sub = lane & 15;        // 8B slot within 128B row (8 fp8 channels)
    int e4  = lane >> 4;        // edge group 0..3
    int h   = sub >> 2;         // head (8 channels per lane, 32 per head)
    const float4* a4 = (const float4*)a_src;
    const uint2* x8  = (const uint2*)xp8;     // 16 uint2 per 128B row
    float psum[8], psq[8];
    #pragma unroll
    for (int k = 0; k < 8; ++k){ psum[k]=0.f; psq[k]=0.f; }
    int ngroups = (n + 3) >> 2;
    for (int grp = blockIdx.x; grp < ngroups; grp += NB_AGGR){
        int node = grp*4 + w;
        if (node >= n) continue;
        float4 ad4 = *(const float4*)(a_dst + node*4);
        float adh = sel4(ad4, h);
        int deg = min(cursor[node], CAP);
        const int* nrow = nbr + (size_t)node*CAP;
        float acc[8];
        #pragma unroll
        for (int k = 0; k < 8; ++k) acc[k] = 0.f;
        float ssum = (e4 == 0) ? __expf(lrelu(a_src[node*4 + h] + adh)) : 0.f;
        float ws = ssum;                              // self weight (e4==0 lanes)
        uint2 xsraw = x8[(size_t)node*16 + sub];      // self row slot (fp8)
        for (int ch0 = 0; ch0 < deg; ch0 += 32){
            int idx = ch0 + lane;
            if (idx > deg-1) idx = deg-1;
            int sidv = (lane < 32) ? nrow[idx] : node;
            float4 av = a4[sidv];
            if (lane < 32){
                float4 w4;
                w4.x = __expf(lrelu(av.x + ad4.x));
                w4.y = __expf(lrelu(av.y + ad4.y));
                w4.z = __expf(lrelu(av.z + ad4.z));
                w4.w = __expf(lrelu(av.w + ad4.w));
                *(float4*)&wlds[w][lane][0] = w4;
            }
            __builtin_amdgcn_wave_barrier();          // order LDS write->read in-wave
            int sid[8];
            #pragma unroll
            for (int p = 0; p < 8; ++p) sid[p] = __shfl(sidv, p*4 + e4);
            uint2 xr[8];
            #pragma unroll
            for (int p = 0; p < 8; ++p) xr[p] = x8[(size_t)sid[p]*16 + sub];
            #pragma unroll
            for (int p = 0; p < 8; ++p){
                int j = p*4 + e4;
                float wgt = ((ch0 + j) < deg) ? wlds[w][j][h] : 0.f;
                ssum += wgt;
                float2 c0 = fp8x2_to_f2<false>(xr[p].x);
                float2 c1 = fp8x2_to_f2<true >(xr[p].x);
                float2 c2 = fp8x2_to_f2<false>(xr[p].y);
                float2 c3 = fp8x2_to_f2<true >(xr[p].y);
                acc[0] += wgt*c0.x; acc[1] += wgt*c0.y;
                acc[2] += wgt*c1.x; acc[3] += wgt*c1.y;
                acc[4] += wgt*c2.x; acc[5] += wgt*c2.y;
                acc[6] += wgt*c3.x; acc[7] += wgt*c3.y;
            }
        }
        // combine the 4 edge groups
        #pragma unroll
        for (int off = 16; off <= 32; off <<= 1){
            #pragma unroll
            for (int k = 0; k < 8; ++k) acc[k] += __shfl_xor(acc[k], off);
            ssum += __shfl_xor(ssum, off);
        }
        float inv = 1.f/(ssum + 1e-16f);
        if (e4 == 0){
            float fs[8];
            float2 s0 = fp8x2_to_f2<false>(xsraw.x);
            float2 s1 = fp8x2_to_f2<true >(xsraw.x);
            float2 s2 = fp8x2_to_f2<false>(xsraw.y);
            float2 s3 = fp8x2_to_f2<true >(xsraw.y);
            fs[0]=s0.x; fs[1]=s0.y; fs[2]=s1.x; fs[3]=s1.y;
            fs[4]=s2.x; fs[5]=s2.y; fs[6]=s3.x; fs[7]=s3.y;
            float4 r0 = *(const float4*)(out + (size_t)node*128 + sub*8);
            float4 r1 = *(const float4*)(out + (size_t)node*128 + sub*8 + 4);
            float4 b0 = *(const float4*)(bias + sub*8);
            float4 b1 = *(const float4*)(bias + sub*8 + 4);
            float o[8];
            o[0] = (acc[0]+ws*fs[0])*inv + r0.x + b0.x; o[1] = (acc[1]+ws*fs[1])*inv + r0.y + b0.y;
            o[2] = (acc[2]+ws*fs[2])*inv + r0.z + b0.z; o[3] = (acc[3]+ws*fs[3])*inv + r0.w + b0.w;
            o[4] = (acc[4]+ws*fs[4])*inv + r1.x + b1.x; o[5] = (acc[5]+ws*fs[5])*inv + r1.y + b1.y;
            o[6] = (acc[6]+ws*fs[6])*inv + r1.z + b1.z; o[7] = (acc[7]+ws*fs[7])*inv + r1.w + b1.w;
            *(float4*)(out + (size_t)node*128 + sub*8)     = make_float4(o[0],o[1],o[2],o[3]);
            *(float4*)(out + (size_t)node*128 + sub*8 + 4) = make_float4(o[4],o[5],o[6],o[7]);
            #pragma unroll
            for (int k = 0; k < 8; ++k){ psum[k] += o[k]; psq[k] += o[k]*o[k]; }
        }
    }
    // epilogue: block-combine in LDS, one atomic per thread into a shadow copy
    if (e4 == 0){
        *(float4*)&lsum[w][sub*8]   = make_float4(psum[0],psum[1],psum[2],psum[3]);
        *(float4*)&lsum[w][sub*8+4] = make_float4(psum[4],psum[5],psum[6],psum[7]);
        *(float4*)&lsq[w][sub*8]    = make_float4(psq[0],psq[1],psq[2],psq[3]);
        *(float4*)&lsq[w][sub*8+4]  = make_float4(psq[4],psq[5],psq[6],psq[7]);
    }
    __syncthreads();
    int t = threadIdx.x;
    float* shad = gshad + (blockIdx.x & (NSHAD-1))*256;
    if (t < 128){
        float s = lsum[0][t]+lsum[1][t]+lsum[2][t]+lsum[3][t];
        atomicAdd(&shad[t], s);
    } else {
        int c = t-128;
        float s = lsq[0][c]+lsq[1][c]+lsq[2][c]+lsq[3][c];
        atomicAdd(&shad[128 + c], s);
    }
}

// ---------------- BN finalize ----------------
__global__ void k_bnfin(const float* __restrict__ gshad,
        const float* __restrict__ gamma, const float* __restrict__ beta,
        float* __restrict__ scale, float* __restrict__ shift, int n){
    int t = threadIdx.x;
    if (t < 128){
        float s = 0.f, q = 0.f;
        #pragma unroll
        for (int c = 0; c < NSHAD; ++c){
            s += gshad[c*256 + t];
            q += gshad[c*256 + 128 + t];
        }
        float mu  = s/(float)n;
        float var = q/(float)n - mu*mu;
        float inv = rsqrtf(var + 1e-5f);
        float sc  = inv*gamma[t];
        scale[t] = sc;
        shift[t] = beta[t] - mu*sc;
    }
}

__global__ __launch_bounds__(256) void k_bnapply(float* __restrict__ out,
        const float* __restrict__ scale, const float* __restrict__ shift, long total4){
    __shared__ float sc[128], sh[128];
    if (threadIdx.x < 128){ sc[threadIdx.x]=scale[threadIdx.x]; sh[threadIdx.x]=shift[threadIdx.x]; }
    __syncthreads();
    long i = (long)blockIdx.x*blockDim.x + threadIdx.x;
    if (i < total4){
        float4* o4 = (float4*)out;
        float4 v = o4[i];
        int c = (int)((i & 31) * 4);
        v.x = v.x*sc[c+0]+sh[c+0];
        v.y = v.y*sc[c+1]+sh[c+1];
        v.z = v.z*sc[c+2]+sh[c+2];
        v.w = v.w*sc[c+3]+sh[c+3];
        o4[i]=v;
    }
}

extern "C" void kernel_launch(void* const* d_in, const int* in_sizes, int n_in,
                              void* d_out, int out_size, void* d_ws, size_t ws_size,
                              hipStream_t stream){
    const float* feats      = (const float*)d_in[0];
    const int* ei           = (const int*)d_in[1];   // harness converts int64 -> int32
    const float* Wsrc       = (const float*)d_in[2];
    const float* att_s      = (const float*)d_in[3];
    const float* att_d      = (const float*)d_in[4];
    const float* Wres       = (const float*)d_in[5];
    const float* bias       = (const float*)d_in[6];
    const float* gamma      = (const float*)d_in[7];
    const float* beta       = (const float*)d_in[8];
    int n = in_sizes[0]/128;
    int e = in_sizes[1]/2;
    float* out = (float*)d_out;

    char* w = (char*)d_ws;
    unsigned char* xp8 = (unsigned char*)w; w += (size_t)n*128;
    float* a_src = (float*)w; w += (size_t)n*4*4;
    float* a_dst = (float*)w; w += (size_t)n*4*4;
    int*   cursor= (int*)w;   w += (size_t)n*4;
    int*   nbr   = (int*)w;   w += (size_t)n*CAP*4;
    float* gshad = (float*)w; w += (size_t)NSHAD*256*4;
    float* scale = (float*)w; w += 512;
    float* shift = (float*)w; w += 512;
    _Float16* WH = (_Float16*)w; w += 32768*2;

    hipMemsetAsync(cursor, 0, (size_t)n*4, stream);
    hipMemsetAsync(gshad,  0, (size_t)NSHAD*256*4, stream);

    k_wcvt<<<dim3(128), 256, 0, stream>>>(Wsrc, Wres, WH);
    k_gemm<<<dim3((n+63)/64), 256, 0, stream>>>(feats, WH, att_s, att_d, xp8, out, a_src, a_dst, n);
    k_scatter<<<dim3(NB_CSR), 256, 0, stream>>>(ei, cursor, nbr, e, n);
    k_aggr<<<dim3(NB_AGGR), 256, 0, stream>>>(xp8, a_src, a_dst, cursor, nbr, bias, out, gshad, n);
    k_bnfin<<<dim3(1), 128, 0, stream>>>(gshad, gamma, beta, scale, shift, n);
    long total4 = (long)n*32;
    k_bnapply<<<dim3((int)((total4+255)/256)), 256, 0, stream>>>(out, scale, shift, total4);
}